// Round 2
// baseline (2792.566 us; speedup 1.0000x reference)
//
#include <hip/hip_runtime.h>
#include <math.h>

#define N_ 8000
#define T_ 16
#define D_ 256
#define E_ 256000
#define ND_ (N_*D_)

// ---------------------------------------------------------------------------
// fuse: U = concat(emb1, demand[:, -1], supply[:, -1]) @ fuse_W + fuse_b
// tile M=128 N=64 BK=16, 256 thr (16x16), micro 8x4
__global__ __launch_bounds__(256) void k_fuse(
    const float* __restrict__ emb1, const float* __restrict__ demand,
    const float* __restrict__ supply, const float* __restrict__ W,
    const float* __restrict__ b, float* __restrict__ U)
{
    __shared__ float As[16][132];
    __shared__ float Bs[16][68];
    const int t = threadIdx.x;
    const int tx = t & 15, ty = t >> 4;
    const int m0 = blockIdx.x * 128, n0 = blockIdx.y * 64;
    float acc[8][4] = {};
    for (int k0 = 0; k0 < 768; k0 += 16) {
#pragma unroll
        for (int i = 0; i < 2; ++i) {
            int f = t + i * 256;
            int row = f >> 2;
            int kg = (f & 3) << 2;
            int gr = m0 + row;
            float4 a = make_float4(0.f, 0.f, 0.f, 0.f);
            if (gr < N_) {
                int k = k0 + kg;
                int kk = k & 255;
                const float* src = (k < 256) ? &emb1[gr * 256 + kk]
                               : (k < 512) ? &demand[gr * 4096 + 3840 + kk]
                                           : &supply[gr * 4096 + 3840 + kk];
                a = *(const float4*)src;
            }
            As[kg + 0][row] = a.x; As[kg + 1][row] = a.y;
            As[kg + 2][row] = a.z; As[kg + 3][row] = a.w;
        }
        {
            float4 bb = *(const float4*)&W[(k0 + (t >> 4)) * 256 + n0 + (t & 15) * 4];
            *(float4*)&Bs[t >> 4][(t & 15) * 4] = bb;
        }
        __syncthreads();
#pragma unroll
        for (int k = 0; k < 16; ++k) {
            float4 a0 = *(const float4*)&As[k][ty * 8];
            float4 a1 = *(const float4*)&As[k][ty * 8 + 4];
            float4 b0 = *(const float4*)&Bs[k][tx * 4];
            float ar[8] = {a0.x, a0.y, a0.z, a0.w, a1.x, a1.y, a1.z, a1.w};
            float br[4] = {b0.x, b0.y, b0.z, b0.w};
#pragma unroll
            for (int ii = 0; ii < 8; ++ii)
#pragma unroll
                for (int jj = 0; jj < 4; ++jj)
                    acc[ii][jj] = fmaf(ar[ii], br[jj], acc[ii][jj]);
        }
        __syncthreads();
    }
#pragma unroll
    for (int ii = 0; ii < 8; ++ii) {
        int gm = m0 + ty * 8 + ii;
        if (gm >= N_) continue;
        int gn = n0 + tx * 4;
        float4 o;
        o.x = acc[ii][0] + b[gn + 0];
        o.y = acc[ii][1] + b[gn + 1];
        o.z = acc[ii][2] + b[gn + 2];
        o.w = acc[ii][3] + b[gn + 3];
        *(float4*)&U[gm * 256 + gn] = o;
    }
}

// ---------------------------------------------------------------------------
// S = U @ U^T (raw logits), tile 128x128 BK=16, micro 8x8
__global__ __launch_bounds__(256) void k_s(const float* __restrict__ U, float* __restrict__ S)
{
    __shared__ float As[16][132];
    __shared__ float Bs[16][132];
    const int t = threadIdx.x;
    const int tx = t & 15, ty = t >> 4;
    const int i0 = blockIdx.x * 128, j0 = blockIdx.y * 128;
    float acc[8][8] = {};
    for (int k0 = 0; k0 < 256; k0 += 16) {
#pragma unroll
        for (int i = 0; i < 2; ++i) {
            int f = t + i * 256;
            int row = f >> 2;
            int kg = (f & 3) << 2;
            int gi = i0 + row;
            float4 a = make_float4(0.f, 0.f, 0.f, 0.f);
            if (gi < N_) a = *(const float4*)&U[gi * 256 + k0 + kg];
            As[kg + 0][row] = a.x; As[kg + 1][row] = a.y;
            As[kg + 2][row] = a.z; As[kg + 3][row] = a.w;
            int gj = j0 + row;
            float4 bb = make_float4(0.f, 0.f, 0.f, 0.f);
            if (gj < N_) bb = *(const float4*)&U[gj * 256 + k0 + kg];
            Bs[kg + 0][row] = bb.x; Bs[kg + 1][row] = bb.y;
            Bs[kg + 2][row] = bb.z; Bs[kg + 3][row] = bb.w;
        }
        __syncthreads();
#pragma unroll
        for (int k = 0; k < 16; ++k) {
            float4 a0 = *(const float4*)&As[k][ty * 8];
            float4 a1 = *(const float4*)&As[k][ty * 8 + 4];
            float4 b0 = *(const float4*)&Bs[k][tx * 8];
            float4 b1 = *(const float4*)&Bs[k][tx * 8 + 4];
            float ar[8] = {a0.x, a0.y, a0.z, a0.w, a1.x, a1.y, a1.z, a1.w};
            float br[8] = {b0.x, b0.y, b0.z, b0.w, b1.x, b1.y, b1.z, b1.w};
#pragma unroll
            for (int ii = 0; ii < 8; ++ii)
#pragma unroll
                for (int jj = 0; jj < 8; ++jj)
                    acc[ii][jj] = fmaf(ar[ii], br[jj], acc[ii][jj]);
        }
        __syncthreads();
    }
#pragma unroll
    for (int ii = 0; ii < 8; ++ii) {
        int gi = i0 + ty * 8 + ii;
        if (gi >= N_) continue;
        int gj = j0 + tx * 8;
        if (gj >= N_) continue;
        size_t base = (size_t)gi * N_ + gj;
        *(float4*)&S[base] = make_float4(acc[ii][0], acc[ii][1], acc[ii][2], acc[ii][3]);
        *(float4*)&S[base + 4] = make_float4(acc[ii][4], acc[ii][5], acc[ii][6], acc[ii][7]);
    }
}

// ---------------------------------------------------------------------------
// per-row max and 1/sum(exp(s-max)); one block per row, 32 values per thread
__global__ __launch_bounds__(256) void k_rowstat(const float* __restrict__ S,
    float* __restrict__ rowmax, float* __restrict__ rowinv)
{
    __shared__ float red[256];
    const int r = blockIdx.x;
    const int t = threadIdx.x;
    const float* row = S + (size_t)r * N_;
    float v[32];
    float m = -3.4e38f;
#pragma unroll
    for (int ch = 0; ch < 8; ++ch) {
        int c = ch * 1024 + t * 4;
        float4 x;
        if (c < N_) x = *(const float4*)&row[c];
        else x = make_float4(-3.4e38f, -3.4e38f, -3.4e38f, -3.4e38f);
        v[ch * 4 + 0] = x.x; v[ch * 4 + 1] = x.y;
        v[ch * 4 + 2] = x.z; v[ch * 4 + 3] = x.w;
        m = fmaxf(m, fmaxf(fmaxf(x.x, x.y), fmaxf(x.z, x.w)));
    }
    red[t] = m; __syncthreads();
    for (int s = 128; s > 0; s >>= 1) { if (t < s) red[t] = fmaxf(red[t], red[t + s]); __syncthreads(); }
    m = red[0]; __syncthreads();
    float sum = 0.f;
#pragma unroll
    for (int j = 0; j < 32; ++j) sum += __expf(v[j] - m);
    red[t] = sum; __syncthreads();
    for (int s = 128; s > 0; s >>= 1) { if (t < s) red[t] += red[t + s]; __syncthreads(); }
    if (t == 0) { rowmax[r] = m; rowinv[r] = 1.0f / red[0]; }
}

// ---------------------------------------------------------------------------
// in-place: pred = relu(exp(S-max)*inv - 0.2), plus column sums for degree
__global__ __launch_bounds__(256) void k_softrelu(float* __restrict__ S,
    const float* __restrict__ rowmax, const float* __restrict__ rowinv,
    float* __restrict__ colsum)
{
    int c = blockIdx.x * 256 + threadIdx.x;
    if (c >= N_) return;
    int r0 = blockIdx.y * 500;
    float cs = 0.f;
    for (int i = 0; i < 500; ++i) {
        int r = r0 + i;
        size_t idx = (size_t)r * N_ + c;
        float p = __expf(S[idx] - rowmax[r]) * rowinv[r];
        float o = fmaxf(p - 0.2f, 0.f);
        S[idx] = o;
        cs += o;
    }
    atomicAdd(&colsum[c], cs);
}

__global__ void k_disd(const float* __restrict__ colsum, float* __restrict__ dis)
{
    int c = blockIdx.x * 256 + threadIdx.x;
    if (c < N_) dis[c] = 1.0f / sqrtf(colsum[c] + 1.0f);
}

// ---------------------------------------------------------------------------
// Out[m][n] = (scale?scale[m]:1) * sum_k A[m][k]*W[k][n]; tile 128x64 BK=16
__global__ __launch_bounds__(256) void k_xw(const float* __restrict__ A,
    const float* __restrict__ W, const float* __restrict__ scale, float* __restrict__ Out)
{
    __shared__ float As[16][132];
    __shared__ float Bs[16][68];
    const int t = threadIdx.x;
    const int tx = t & 15, ty = t >> 4;
    const int m0 = blockIdx.x * 128, n0 = blockIdx.y * 64;
    float acc[8][4] = {};
    for (int k0 = 0; k0 < 256; k0 += 16) {
#pragma unroll
        for (int i = 0; i < 2; ++i) {
            int f = t + i * 256;
            int row = f >> 2;
            int kg = (f & 3) << 2;
            int gr = m0 + row;
            float4 a = make_float4(0.f, 0.f, 0.f, 0.f);
            if (gr < N_) a = *(const float4*)&A[gr * 256 + k0 + kg];
            As[kg + 0][row] = a.x; As[kg + 1][row] = a.y;
            As[kg + 2][row] = a.z; As[kg + 3][row] = a.w;
        }
        {
            float4 bb = *(const float4*)&W[(k0 + (t >> 4)) * 256 + n0 + (t & 15) * 4];
            *(float4*)&Bs[t >> 4][(t & 15) * 4] = bb;
        }
        __syncthreads();
#pragma unroll
        for (int k = 0; k < 16; ++k) {
            float4 a0 = *(const float4*)&As[k][ty * 8];
            float4 a1 = *(const float4*)&As[k][ty * 8 + 4];
            float4 b0 = *(const float4*)&Bs[k][tx * 4];
            float ar[8] = {a0.x, a0.y, a0.z, a0.w, a1.x, a1.y, a1.z, a1.w};
            float br[4] = {b0.x, b0.y, b0.z, b0.w};
#pragma unroll
            for (int ii = 0; ii < 8; ++ii)
#pragma unroll
                for (int jj = 0; jj < 4; ++jj)
                    acc[ii][jj] = fmaf(ar[ii], br[jj], acc[ii][jj]);
        }
        __syncthreads();
    }
#pragma unroll
    for (int ii = 0; ii < 8; ++ii) {
        int gm = m0 + ty * 8 + ii;
        if (gm >= N_) continue;
        float s = scale ? scale[gm] : 1.0f;
        float4 o = make_float4(acc[ii][0] * s, acc[ii][1] * s, acc[ii][2] * s, acc[ii][3] * s);
        *(float4*)&Out[gm * 256 + n0 + tx * 4] = o;
    }
}

// ---------------------------------------------------------------------------
// Z[c][d] += sum_r P[r][c]*Y[r][d]; c-tile 128, d-tile 128, split-K 4x2000 w/ atomics
__global__ __launch_bounds__(256) void k_zmm(const float* __restrict__ P,
    const float* __restrict__ Y, float* __restrict__ Z)
{
    __shared__ float Ps[16][132];
    __shared__ float Ys[16][132];
    const int t = threadIdx.x;
    const int tx = t & 15, ty = t >> 4;
    const int c0 = blockIdx.x * 128;
    const int d0 = blockIdx.y * 128;
    const int r0 = blockIdx.z * 2000;
    float acc[8][8] = {};
    for (int rb = 0; rb < 2000; rb += 16) {
#pragma unroll
        for (int i = 0; i < 2; ++i) {
            int f = t + i * 256;
            int rr = f >> 5;
            int col = (f & 31) << 2;
            int r = r0 + rb + rr;
            int gc = c0 + col;
            float4 p = make_float4(0.f, 0.f, 0.f, 0.f);
            if (gc < N_) p = *(const float4*)&P[(size_t)r * N_ + gc];
            *(float4*)&Ps[rr][col] = p;
            float4 yv = *(const float4*)&Y[r * 256 + d0 + col];
            *(float4*)&Ys[rr][col] = yv;
        }
        __syncthreads();
#pragma unroll
        for (int k = 0; k < 16; ++k) {
            float4 a0 = *(const float4*)&Ps[k][ty * 8];
            float4 a1 = *(const float4*)&Ps[k][ty * 8 + 4];
            float4 b0 = *(const float4*)&Ys[k][tx * 8];
            float4 b1 = *(const float4*)&Ys[k][tx * 8 + 4];
            float ar[8] = {a0.x, a0.y, a0.z, a0.w, a1.x, a1.y, a1.z, a1.w};
            float br[8] = {b0.x, b0.y, b0.z, b0.w, b1.x, b1.y, b1.z, b1.w};
#pragma unroll
            for (int ii = 0; ii < 8; ++ii)
#pragma unroll
                for (int jj = 0; jj < 8; ++jj)
                    acc[ii][jj] = fmaf(ar[ii], br[jj], acc[ii][jj]);
        }
        __syncthreads();
    }
#pragma unroll
    for (int ii = 0; ii < 8; ++ii) {
        int gc = c0 + ty * 8 + ii;
        if (gc >= N_) continue;
        int gd = d0 + tx * 8;
#pragma unroll
        for (int jj = 0; jj < 8; ++jj)
            atomicAdd(&Z[gc * 256 + gd + jj], acc[ii][jj]);
    }
}

// t_new = 0.9*(dis[c]*(z+y) + b) + 0.1*t_old
__global__ void k_dfinish(const float* __restrict__ Zb, const float* __restrict__ Yb,
    const float* __restrict__ disd, const float* __restrict__ b,
    const float* __restrict__ told, float* __restrict__ tnew)
{
    int i = blockIdx.x * 256 + threadIdx.x;
    int idx = i * 4;
    int c = idx >> 8;
    int d = idx & 255;
    float dc = disd[c];
    float4 zv = *(const float4*)&Zb[idx];
    float4 yv = *(const float4*)&Yb[idx];
    float4 tv = *(const float4*)&told[idx];
    float4 bb = *(const float4*)&b[d];
    float4 o;
    o.x = 0.9f * (dc * (zv.x + yv.x) + bb.x) + 0.1f * tv.x;
    o.y = 0.9f * (dc * (zv.y + yv.y) + bb.y) + 0.1f * tv.y;
    o.z = 0.9f * (dc * (zv.z + yv.z) + bb.z) + 0.1f * tv.z;
    o.w = 0.9f * (dc * (zv.w + yv.w) + bb.w) + 0.1f * tv.w;
    *(float4*)&tnew[idx] = o;
}

// ---------------------------------------------------------------------------
// sparse graph: counting sort by dst, then per-node aggregation
__global__ void k_hist(const int* __restrict__ dst, int* __restrict__ cnt)
{
    int e = blockIdx.x * 256 + threadIdx.x;
    if (e < E_) atomicAdd(&cnt[dst[e]], 1);
}

__global__ __launch_bounds__(1024) void k_scan(const int* __restrict__ cnt, int* __restrict__ offs)
{
    __shared__ int sh[1024];
    int t = threadIdx.x;
    int base = t * 8;
    int v[8];
    int s = 0;
#pragma unroll
    for (int j = 0; j < 8; ++j) {
        v[j] = s;
        int bb = base + j;
        s += (bb < N_) ? cnt[bb] : 0;
    }
    sh[t] = s;
    __syncthreads();
    for (int o = 1; o < 1024; o <<= 1) {
        int x = sh[t];
        int y = (t >= o) ? sh[t - o] : 0;
        __syncthreads();
        sh[t] = x + y;
        __syncthreads();
    }
    int pre = (t == 0) ? 0 : sh[t - 1];
#pragma unroll
    for (int j = 0; j < 8; ++j) {
        int bb = base + j;
        if (bb < N_) offs[bb] = pre + v[j];
    }
    if (t == 1023) offs[N_] = sh[1023];
}

__global__ void k_scatter(const int* __restrict__ dst, const int* __restrict__ offs,
    int* __restrict__ curs, int* __restrict__ sorted)
{
    int e = blockIdx.x * 256 + threadIdx.x;
    if (e < E_) {
        int d = dst[e];
        int pos = offs[d] + atomicAdd(&curs[d], 1);
        sorted[pos] = e;
    }
}

__global__ void k_degs(const int* __restrict__ dst, const float* __restrict__ attr,
    float* __restrict__ degs)
{
    int e = blockIdx.x * 256 + threadIdx.x;
    if (e < E_) atomicAdd(&degs[dst[e]], attr[e]);
}

__global__ void k_diss(const float* __restrict__ degs, float* __restrict__ dis)
{
    int n = blockIdx.x * 256 + threadIdx.x;
    if (n < N_) dis[n] = 1.0f / sqrtf(degs[n] + 1.0f);
}

__global__ void k_enorm(const int* __restrict__ src, const int* __restrict__ dst,
    const float* __restrict__ attr, const float* __restrict__ dis, float* __restrict__ enorm)
{
    int e = blockIdx.x * 256 + threadIdx.x;
    if (e < E_) enorm[e] = dis[src[e]] * attr[e] * dis[dst[e]];
}

// per dst-node block: agg over its edges + self term + residual blend
__global__ __launch_bounds__(256) void k_sfinish(const int* __restrict__ offs,
    const int* __restrict__ sorted, const float* __restrict__ enorm,
    const int* __restrict__ src, const float* __restrict__ xw,
    const float* __restrict__ diss, const float* __restrict__ b,
    const float* __restrict__ told, float* __restrict__ tnew)
{
    int n = blockIdx.x;
    int t = threadIdx.x;
    float acc = 0.f;
    int beg = offs[n], end = offs[n + 1];
    for (int i = beg; i < end; ++i) {
        int e = sorted[i];
        float w = enorm[e];
        int s = src[e];
        acc += w * xw[s * 256 + t];
    }
    float sn = diss[n];
    sn *= sn;
    float out = acc + sn * xw[n * 256 + t] + b[t];
    tnew[n * 256 + t] = 0.9f * out + 0.1f * told[n * 256 + t];
}

// o += a (elementwise, in-place add into the skill_embs output slot)
__global__ void k_combine(const float* __restrict__ a, float* __restrict__ o)
{
    int i = blockIdx.x * 256 + threadIdx.x;
    int idx = i * 4;
    float4 x = *(const float4*)&a[idx];
    float4 y = *(const float4*)&o[idx];
    *(float4*)&o[idx] = make_float4(x.x + y.x, x.y + y.y, x.z + y.z, x.w + y.w);
}

// ---------------------------------------------------------------------------
extern "C" void kernel_launch(void* const* d_in, const int* in_sizes, int n_in,
                              void* d_out, int out_size, void* d_ws, size_t ws_size,
                              hipStream_t stream)
{
    const float* demand = (const float*)d_in[0];
    const float* supply = (const float*)d_in[1];
    const int* eidx = (const int*)d_in[2];
    const float* eattr = (const float*)d_in[3];
    const float* emb1 = (const float*)d_in[4];
    const float* fuseW = (const float*)d_in[5];
    const float* fuseB = (const float*)d_in[6];
    const float* g0W = (const float*)d_in[7];
    const float* g0B = (const float*)d_in[8];
    const float* g1W = (const float*)d_in[9];
    const float* g1B = (const float*)d_in[10];

    float* out = (float*)d_out;
    float* out_skill = out + ND_;
    float* pred = out + 2 * (size_t)ND_;

    float* ws = (float*)d_ws;
    float* U = ws;
    float* TD = U + ND_;
    float* YB = TD + ND_;
    float* Zb = YB + ND_;
    float* TS = out_skill;          // sparse-stack temp lives in the output slot
    float* ROWMAX = Zb + ND_;
    float* ROWINV = ROWMAX + N_;
    float* COLSUM = ROWINV + N_;
    float* DISD = COLSUM + N_;
    float* DEGS = DISD + N_;
    float* DISS = DEGS + N_;
    float* ENORM = DISS + N_;
    int* CNT = (int*)(ENORM + E_);
    int* CURS = CNT + N_;
    int* OFFS = CURS + N_;
    int* SORTED = OFFS + (N_ + 1);

    const int* esrc = eidx;
    const int* edst = eidx + E_;

    // fuse + adaptive adjacency
    k_fuse<<<dim3(63, 4), 256, 0, stream>>>(emb1, demand, supply, fuseW, fuseB, U);
    k_s<<<dim3(63, 63), 256, 0, stream>>>(U, pred);
    k_rowstat<<<N_, 256, 0, stream>>>(pred, ROWMAX, ROWINV);
    hipMemsetAsync(COLSUM, 0, N_ * sizeof(float), stream);
    k_softrelu<<<dim3(32, 16), 256, 0, stream>>>(pred, ROWMAX, ROWINV, COLSUM);
    k_disd<<<32, 256, 0, stream>>>(COLSUM, DISD);

    // dense GCN stack (2 layers)
    const float* told = U;
    for (int l = 0; l < 2; ++l) {
        k_xw<<<dim3(63, 4), 256, 0, stream>>>(told, g0W + l * D_ * D_, DISD, YB);
        hipMemsetAsync(Zb, 0, (size_t)ND_ * sizeof(float), stream);
        k_zmm<<<dim3(63, 2, 4), 256, 0, stream>>>(pred, YB, Zb);
        k_dfinish<<<2000, 256, 0, stream>>>(Zb, YB, DISD, g0B + l * D_, told, TD);
        told = TD;
    }

    // sparse GCN stack: sort edges by dst once
    hipMemsetAsync(CNT, 0, 2 * N_ * sizeof(int), stream);  // CNT + CURS
    hipMemsetAsync(DEGS, 0, N_ * sizeof(float), stream);
    k_hist<<<E_ / 256, 256, 0, stream>>>(edst, CNT);
    k_scan<<<1, 1024, 0, stream>>>(CNT, OFFS);
    k_scatter<<<E_ / 256, 256, 0, stream>>>(edst, OFFS, CURS, SORTED);
    k_degs<<<E_ / 256, 256, 0, stream>>>(edst, eattr, DEGS);
    k_diss<<<32, 256, 0, stream>>>(DEGS, DISS);
    k_enorm<<<E_ / 256, 256, 0, stream>>>(esrc, edst, eattr, DISS, ENORM);

    told = U;
    for (int l = 0; l < 2; ++l) {
        k_xw<<<dim3(63, 4), 256, 0, stream>>>(told, g1W + l * D_ * D_, nullptr, YB);
        k_sfinish<<<N_, 256, 0, stream>>>(OFFS, SORTED, ENORM, esrc, YB, DISS,
                                          g1B + l * D_, told, TS);
        told = TS;
    }

    // outputs: out_skill (=TS) += TD ; emb1 passthrough
    k_combine<<<2000, 256, 0, stream>>>(TD, out_skill);
    hipMemcpyAsync(out, emb1, (size_t)ND_ * sizeof(float), hipMemcpyDeviceToDevice, stream);
}

// Round 4
// 1300.672 us; speedup vs baseline: 2.1470x; 2.1470x over previous
//
#include <hip/hip_runtime.h>
#include <math.h>

#define N_ 8000
#define T_ 16
#define D_ 256
#define E_ 256000
#define ND_ (N_*D_)
#define CAP_ 32768   // nnz(pred) <= 4 per row * 8000 rows, mathematically

typedef __attribute__((ext_vector_type(8))) short bf16x8;
typedef __attribute__((ext_vector_type(4))) float f32x4;

// ---------------------------------------------------------------------------
// fuse: U = concat(emb1, demand[:, -1], supply[:, -1]) @ fuse_W + fuse_b
__global__ __launch_bounds__(256) void k_fuse(
    const float* __restrict__ emb1, const float* __restrict__ demand,
    const float* __restrict__ supply, const float* __restrict__ W,
    const float* __restrict__ b, float* __restrict__ U)
{
    __shared__ float As[16][132];
    __shared__ float Bs[16][68];
    const int t = threadIdx.x;
    const int tx = t & 15, ty = t >> 4;
    const int m0 = blockIdx.x * 128, n0 = blockIdx.y * 64;
    float acc[8][4] = {};
    for (int k0 = 0; k0 < 768; k0 += 16) {
#pragma unroll
        for (int i = 0; i < 2; ++i) {
            int f = t + i * 256;
            int row = f >> 2;
            int kg = (f & 3) << 2;
            int gr = m0 + row;
            float4 a = make_float4(0.f, 0.f, 0.f, 0.f);
            if (gr < N_) {
                int k = k0 + kg;
                int kk = k & 255;
                const float* src = (k < 256) ? &emb1[gr * 256 + kk]
                               : (k < 512) ? &demand[gr * 4096 + 3840 + kk]
                                           : &supply[gr * 4096 + 3840 + kk];
                a = *(const float4*)src;
            }
            As[kg + 0][row] = a.x; As[kg + 1][row] = a.y;
            As[kg + 2][row] = a.z; As[kg + 3][row] = a.w;
        }
        {
            float4 bb = *(const float4*)&W[(k0 + (t >> 4)) * 256 + n0 + (t & 15) * 4];
            *(float4*)&Bs[t >> 4][(t & 15) * 4] = bb;
        }
        __syncthreads();
#pragma unroll
        for (int k = 0; k < 16; ++k) {
            float4 a0 = *(const float4*)&As[k][ty * 8];
            float4 a1 = *(const float4*)&As[k][ty * 8 + 4];
            float4 b0 = *(const float4*)&Bs[k][tx * 4];
            float ar[8] = {a0.x, a0.y, a0.z, a0.w, a1.x, a1.y, a1.z, a1.w};
            float br[4] = {b0.x, b0.y, b0.z, b0.w};
#pragma unroll
            for (int ii = 0; ii < 8; ++ii)
#pragma unroll
                for (int jj = 0; jj < 4; ++jj)
                    acc[ii][jj] = fmaf(ar[ii], br[jj], acc[ii][jj]);
        }
        __syncthreads();
    }
#pragma unroll
    for (int ii = 0; ii < 8; ++ii) {
        int gm = m0 + ty * 8 + ii;
        if (gm >= N_) continue;
        int gn = n0 + tx * 4;
        float4 o;
        o.x = acc[ii][0] + b[gn + 0];
        o.y = acc[ii][1] + b[gn + 1];
        o.z = acc[ii][2] + b[gn + 2];
        o.w = acc[ii][3] + b[gn + 3];
        *(float4*)&U[gm * 256 + gn] = o;
    }
}

// ---------------------------------------------------------------------------
// split U (fp32) into hi/lo bf16 (round-to-nearest-even): U ~= hi + lo
__device__ __forceinline__ unsigned short f2bf(float f, float* back) {
    union { float f; unsigned u; } c; c.f = f;
    unsigned r = (c.u + 0x7fffu + ((c.u >> 16) & 1u)) & 0xffff0000u;
    union { unsigned u; float f; } o; o.u = r;
    *back = o.f;
    return (unsigned short)(r >> 16);
}

__global__ void k_split(const float* __restrict__ U, unsigned short* __restrict__ hi,
                        unsigned short* __restrict__ lo)
{
    int i = (blockIdx.x * 256 + threadIdx.x) * 4;
    float4 u = *(const float4*)&U[i];
    float bh;
    unsigned short h0 = f2bf(u.x, &bh); float l0f = u.x - bh;
    unsigned short h1 = f2bf(u.y, &bh); float l1f = u.y - bh;
    unsigned short h2 = f2bf(u.z, &bh); float l2f = u.z - bh;
    unsigned short h3 = f2bf(u.w, &bh); float l3f = u.w - bh;
    unsigned short l0 = f2bf(l0f, &bh);
    unsigned short l1 = f2bf(l1f, &bh);
    unsigned short l2 = f2bf(l2f, &bh);
    unsigned short l3 = f2bf(l3f, &bh);
    uint2 hv, lv;
    hv.x = (unsigned)h0 | ((unsigned)h1 << 16);
    hv.y = (unsigned)h2 | ((unsigned)h3 << 16);
    lv.x = (unsigned)l0 | ((unsigned)l1 << 16);
    lv.y = (unsigned)l2 | ((unsigned)l3 << 16);
    *(uint2*)&hi[i] = hv;
    *(uint2*)&lo[i] = lv;
}

// ---------------------------------------------------------------------------
// S = U @ U^T via split-bf16 MFMA: S ~= hi*hi + hi*lo + lo*hi (fp32 acc).
// block 128x128, 4 waves 2x2, wave 64x64 = 4x4 mfma_f32_16x16x32_bf16 tiles.
__global__ __launch_bounds__(256) void k_s_mfma(
    const unsigned short* __restrict__ Uhi, const unsigned short* __restrict__ Ulo,
    float* __restrict__ S)
{
    __shared__ unsigned short Ah[4][128][8];   // [kgroup][row][j] 8KB each
    __shared__ unsigned short Al[4][128][8];
    __shared__ unsigned short Bh[4][128][8];
    __shared__ unsigned short Bl[4][128][8];
    const int t = threadIdx.x;
    const int wave = t >> 6, lane = t & 63;
    const int wr = wave >> 1, wc = wave & 1;
    const int i0 = blockIdx.x * 128, j0 = blockIdx.y * 128;
    const int g = lane >> 4, rr = lane & 15;

    f32x4 acc[4][4];
#pragma unroll
    for (int m = 0; m < 4; ++m)
#pragma unroll
        for (int n = 0; n < 4; ++n) acc[m][n] = (f32x4){0.f, 0.f, 0.f, 0.f};

    for (int k0 = 0; k0 < 256; k0 += 32) {
        // stage A/B hi+lo tiles: 512 chunks of 16B per part, 2 per thread
#pragma unroll
        for (int i = 0; i < 2; ++i) {
            int cid = t + i * 256;          // 0..511
            int r = cid >> 2, gg = cid & 3; // row-in-tile, kgroup
            int off = k0 + gg * 8;
            uint4 z = make_uint4(0u, 0u, 0u, 0u);
            uint4 vah = z, val = z, vbh = z, vbl = z;
            int ga = i0 + r, gb = j0 + r;
            if (ga < N_) {
                vah = *(const uint4*)&Uhi[ga * 256 + off];
                val = *(const uint4*)&Ulo[ga * 256 + off];
            }
            if (gb < N_) {
                vbh = *(const uint4*)&Uhi[gb * 256 + off];
                vbl = *(const uint4*)&Ulo[gb * 256 + off];
            }
            *(uint4*)&Ah[gg][r][0] = vah;
            *(uint4*)&Al[gg][r][0] = val;
            *(uint4*)&Bh[gg][r][0] = vbh;
            *(uint4*)&Bl[gg][r][0] = vbl;
        }
        __syncthreads();

        bf16x8 ah[4], al[4], bh[4], bl[4];
#pragma unroll
        for (int m = 0; m < 4; ++m) {
            int row = wr * 64 + m * 16 + rr;
            ah[m] = *(const bf16x8*)&Ah[g][row][0];
            al[m] = *(const bf16x8*)&Al[g][row][0];
        }
#pragma unroll
        for (int n = 0; n < 4; ++n) {
            int col = wc * 64 + n * 16 + rr;
            bh[n] = *(const bf16x8*)&Bh[g][col][0];
            bl[n] = *(const bf16x8*)&Bl[g][col][0];
        }
#pragma unroll
        for (int m = 0; m < 4; ++m)
#pragma unroll
            for (int n = 0; n < 4; ++n) {
                acc[m][n] = __builtin_amdgcn_mfma_f32_16x16x32_bf16(ah[m], bh[n], acc[m][n], 0, 0, 0);
                acc[m][n] = __builtin_amdgcn_mfma_f32_16x16x32_bf16(ah[m], bl[n], acc[m][n], 0, 0, 0);
                acc[m][n] = __builtin_amdgcn_mfma_f32_16x16x32_bf16(al[m], bh[n], acc[m][n], 0, 0, 0);
            }
        __syncthreads();
    }

    // C/D layout (HW-verified): col = lane&15, row = (lane>>4)*4 + reg
#pragma unroll
    for (int m = 0; m < 4; ++m) {
        int gi_base = i0 + wr * 64 + m * 16 + g * 4;
#pragma unroll
        for (int n = 0; n < 4; ++n) {
            int gj = j0 + wc * 64 + n * 16 + rr;
            if (gj >= N_) continue;
#pragma unroll
            for (int j = 0; j < 4; ++j) {
                int gi = gi_base + j;
                if (gi < N_) S[(size_t)gi * N_ + gj] = acc[m][n][j];
            }
        }
    }
}

// ---------------------------------------------------------------------------
// per-row max and 1/sum(exp(s-max))
__global__ __launch_bounds__(256) void k_rowstat(const float* __restrict__ S,
    float* __restrict__ rowmax, float* __restrict__ rowinv)
{
    __shared__ float red[256];
    const int r = blockIdx.x;
    const int t = threadIdx.x;
    const float* row = S + (size_t)r * N_;
    float v[32];
    float m = -3.4e38f;
#pragma unroll
    for (int ch = 0; ch < 8; ++ch) {
        int c = ch * 1024 + t * 4;
        float4 x;
        if (c < N_) x = *(const float4*)&row[c];
        else x = make_float4(-3.4e38f, -3.4e38f, -3.4e38f, -3.4e38f);
        v[ch * 4 + 0] = x.x; v[ch * 4 + 1] = x.y;
        v[ch * 4 + 2] = x.z; v[ch * 4 + 3] = x.w;
        m = fmaxf(m, fmaxf(fmaxf(x.x, x.y), fmaxf(x.z, x.w)));
    }
    red[t] = m; __syncthreads();
    for (int s = 128; s > 0; s >>= 1) { if (t < s) red[t] = fmaxf(red[t], red[t + s]); __syncthreads(); }
    m = red[0]; __syncthreads();
    float sum = 0.f;
#pragma unroll
    for (int j = 0; j < 32; ++j) sum += __expf(v[j] - m);
    red[t] = sum; __syncthreads();
    for (int s = 128; s > 0; s >>= 1) { if (t < s) red[t] += red[t + s]; __syncthreads(); }
    if (t == 0) { rowmax[r] = m; rowinv[r] = 1.0f / red[0]; }
}

// ---------------------------------------------------------------------------
// in-place pred = relu(softmax - 0.2); column sums; sparse nonzero extraction
__global__ __launch_bounds__(256) void k_softrelu(float* __restrict__ S,
    const float* __restrict__ rowmax, const float* __restrict__ rowinv,
    float* __restrict__ colsum, int* __restrict__ nnz,
    int* __restrict__ NZR, int* __restrict__ NZC, float* __restrict__ NZV)
{
    int c = blockIdx.x * 256 + threadIdx.x;
    if (c >= N_) return;
    int r0 = blockIdx.y * 500;
    float cs = 0.f;
    for (int i = 0; i < 500; ++i) {
        int r = r0 + i;
        size_t idx = (size_t)r * N_ + c;
        float p = __expf(S[idx] - rowmax[r]) * rowinv[r];
        float o = fmaxf(p - 0.2f, 0.f);
        S[idx] = o;
        cs += o;
        if (o > 0.f) {
            int id = atomicAdd(nnz, 1);
            if (id < CAP_) { NZR[id] = r; NZC[id] = c; NZV[id] = o; }
        }
    }
    atomicAdd(&colsum[c], cs);
}

__global__ void k_disd(const float* __restrict__ colsum, float* __restrict__ dis)
{
    int c = blockIdx.x * 256 + threadIdx.x;
    if (c < N_) dis[c] = 1.0f / sqrtf(colsum[c] + 1.0f);
}

// ---------------------------------------------------------------------------
// Out[m][n] = (scale?scale[m]:1) * sum_k A[m][k]*W[k][n]
__global__ __launch_bounds__(256) void k_xw(const float* __restrict__ A,
    const float* __restrict__ W, const float* __restrict__ scale, float* __restrict__ Out)
{
    __shared__ float As[16][132];
    __shared__ float Bs[16][68];
    const int t = threadIdx.x;
    const int tx = t & 15, ty = t >> 4;
    const int m0 = blockIdx.x * 128, n0 = blockIdx.y * 64;
    float acc[8][4] = {};
    for (int k0 = 0; k0 < 256; k0 += 16) {
#pragma unroll
        for (int i = 0; i < 2; ++i) {
            int f = t + i * 256;
            int row = f >> 2;
            int kg = (f & 3) << 2;
            int gr = m0 + row;
            float4 a = make_float4(0.f, 0.f, 0.f, 0.f);
            if (gr < N_) a = *(const float4*)&A[gr * 256 + k0 + kg];
            As[kg + 0][row] = a.x; As[kg + 1][row] = a.y;
            As[kg + 2][row] = a.z; As[kg + 3][row] = a.w;
        }
        {
            float4 bb = *(const float4*)&W[(k0 + (t >> 4)) * 256 + n0 + (t & 15) * 4];
            *(float4*)&Bs[t >> 4][(t & 15) * 4] = bb;
        }
        __syncthreads();
#pragma unroll
        for (int k = 0; k < 16; ++k) {
            float4 a0 = *(const float4*)&As[k][ty * 8];
            float4 a1 = *(const float4*)&As[k][ty * 8 + 4];
            float4 b0 = *(const float4*)&Bs[k][tx * 4];
            float ar[8] = {a0.x, a0.y, a0.z, a0.w, a1.x, a1.y, a1.z, a1.w};
            float br[4] = {b0.x, b0.y, b0.z, b0.w};
#pragma unroll
            for (int ii = 0; ii < 8; ++ii)
#pragma unroll
                for (int jj = 0; jj < 4; ++jj)
                    acc[ii][jj] = fmaf(ar[ii], br[jj], acc[ii][jj]);
        }
        __syncthreads();
    }
#pragma unroll
    for (int ii = 0; ii < 8; ++ii) {
        int gm = m0 + ty * 8 + ii;
        if (gm >= N_) continue;
        float s = scale ? scale[gm] : 1.0f;
        float4 o = make_float4(acc[ii][0] * s, acc[ii][1] * s, acc[ii][2] * s, acc[ii][3] * s);
        *(float4*)&Out[gm * 256 + n0 + tx * 4] = o;
    }
}

// ---------------------------------------------------------------------------
// sparse dense-graph aggregation: Z[c,:] += v * Y[r,:] per nonzero (1 wave each)
__global__ __launch_bounds__(256) void k_zsp(const int* __restrict__ nnz,
    const int* __restrict__ NZR, const int* __restrict__ NZC, const float* __restrict__ NZV,
    const float* __restrict__ Y, float* __restrict__ Z)
{
    int n = *nnz; if (n > CAP_) n = CAP_;
    int id = blockIdx.x * 4 + (threadIdx.x >> 6);
    if (id >= n) return;
    int r = NZR[id], c = NZC[id];
    float v = NZV[id];
    int lane = threadIdx.x & 63;
    float4 y = *(const float4*)&Y[r * 256 + lane * 4];
    float* z = &Z[c * 256 + lane * 4];
    atomicAdd(z + 0, v * y.x);
    atomicAdd(z + 1, v * y.y);
    atomicAdd(z + 2, v * y.z);
    atomicAdd(z + 3, v * y.w);
}

// t_new = 0.9*(dis[c]*(z+y) + b) + 0.1*t_old
__global__ void k_dfinish(const float* __restrict__ Zb, const float* __restrict__ Yb,
    const float* __restrict__ disd, const float* __restrict__ b,
    const float* __restrict__ told, float* __restrict__ tnew)
{
    int i = blockIdx.x * 256 + threadIdx.x;
    int idx = i * 4;
    int c = idx >> 8;
    int d = idx & 255;
    float dc = disd[c];
    float4 zv = *(const float4*)&Zb[idx];
    float4 yv = *(const float4*)&Yb[idx];
    float4 tv = *(const float4*)&told[idx];
    float4 bb = *(const float4*)&b[d];
    float4 o;
    o.x = 0.9f * (dc * (zv.x + yv.x) + bb.x) + 0.1f * tv.x;
    o.y = 0.9f * (dc * (zv.y + yv.y) + bb.y) + 0.1f * tv.y;
    o.z = 0.9f * (dc * (zv.z + yv.z) + bb.z) + 0.1f * tv.z;
    o.w = 0.9f * (dc * (zv.w + yv.w) + bb.w) + 0.1f * tv.w;
    *(float4*)&tnew[idx] = o;
}

// ---------------------------------------------------------------------------
// sparse provided graph: counting sort by dst, then per-node aggregation
__global__ void k_hist(const int* __restrict__ dst, int* __restrict__ cnt)
{
    int e = blockIdx.x * 256 + threadIdx.x;
    if (e < E_) atomicAdd(&cnt[dst[e]], 1);
}

__global__ __launch_bounds__(1024) void k_scan(const int* __restrict__ cnt, int* __restrict__ offs)
{
    __shared__ int sh[1024];
    int t = threadIdx.x;
    int base = t * 8;
    int v[8];
    int s = 0;
#pragma unroll
    for (int j = 0; j < 8; ++j) {
        v[j] = s;
        int bb = base + j;
        s += (bb < N_) ? cnt[bb] : 0;
    }
    sh[t] = s;
    __syncthreads();
    for (int o = 1; o < 1024; o <<= 1) {
        int x = sh[t];
        int y = (t >= o) ? sh[t - o] : 0;
        __syncthreads();
        sh[t] = x + y;
        __syncthreads();
    }
    int pre = (t == 0) ? 0 : sh[t - 1];
#pragma unroll
    for (int j = 0; j < 8; ++j) {
        int bb = base + j;
        if (bb < N_) offs[bb] = pre + v[j];
    }
    if (t == 1023) offs[N_] = sh[1023];
}

__global__ void k_scatter(const int* __restrict__ dst, const int* __restrict__ offs,
    int* __restrict__ curs, int* __restrict__ sorted)
{
    int e = blockIdx.x * 256 + threadIdx.x;
    if (e < E_) {
        int d = dst[e];
        int pos = offs[d] + atomicAdd(&curs[d], 1);
        sorted[pos] = e;
    }
}

__global__ void k_degs(const int* __restrict__ dst, const float* __restrict__ attr,
    float* __restrict__ degs)
{
    int e = blockIdx.x * 256 + threadIdx.x;
    if (e < E_) atomicAdd(&degs[dst[e]], attr[e]);
}

__global__ void k_diss(const float* __restrict__ degs, float* __restrict__ dis)
{
    int n = blockIdx.x * 256 + threadIdx.x;
    if (n < N_) dis[n] = 1.0f / sqrtf(degs[n] + 1.0f);
}

__global__ void k_enorm(const int* __restrict__ src, const int* __restrict__ dst,
    const float* __restrict__ attr, const float* __restrict__ dis, float* __restrict__ enorm)
{
    int e = blockIdx.x * 256 + threadIdx.x;
    if (e < E_) enorm[e] = dis[src[e]] * attr[e] * dis[dst[e]];
}

__global__ __launch_bounds__(256) void k_sfinish(const int* __restrict__ offs,
    const int* __restrict__ sorted, const float* __restrict__ enorm,
    const int* __restrict__ src, const float* __restrict__ xw,
    const float* __restrict__ diss, const float* __restrict__ b,
    const float* __restrict__ told, float* __restrict__ tnew)
{
    int n = blockIdx.x;
    int t = threadIdx.x;
    float acc = 0.f;
    int beg = offs[n], end = offs[n + 1];
    for (int i = beg; i < end; ++i) {
        int e = sorted[i];
        float w = enorm[e];
        int s = src[e];
        acc += w * xw[s * 256 + t];
    }
    float sn = diss[n];
    sn *= sn;
    float out = acc + sn * xw[n * 256 + t] + b[t];
    tnew[n * 256 + t] = 0.9f * out + 0.1f * told[n * 256 + t];
}

// o += a (in-place add into skill_embs output slot)
__global__ void k_combine(const float* __restrict__ a, float* __restrict__ o)
{
    int i = blockIdx.x * 256 + threadIdx.x;
    int idx = i * 4;
    float4 x = *(const float4*)&a[idx];
    float4 y = *(const float4*)&o[idx];
    *(float4*)&o[idx] = make_float4(x.x + y.x, x.y + y.y, x.z + y.z, x.w + y.w);
}

// ---------------------------------------------------------------------------
extern "C" void kernel_launch(void* const* d_in, const int* in_sizes, int n_in,
                              void* d_out, int out_size, void* d_ws, size_t ws_size,
                              hipStream_t stream)
{
    const float* demand = (const float*)d_in[0];
    const float* supply = (const float*)d_in[1];
    const int* eidx = (const int*)d_in[2];
    const float* eattr = (const float*)d_in[3];
    const float* emb1 = (const float*)d_in[4];
    const float* fuseW = (const float*)d_in[5];
    const float* fuseB = (const float*)d_in[6];
    const float* g0W = (const float*)d_in[7];
    const float* g0B = (const float*)d_in[8];
    const float* g1W = (const float*)d_in[9];
    const float* g1B = (const float*)d_in[10];

    float* out = (float*)d_out;
    float* out_skill = out + ND_;
    float* pred = out + 2 * (size_t)ND_;

    float* ws = (float*)d_ws;
    float* U = ws;
    float* TD = U + ND_;
    float* YB = TD + ND_;
    float* Zb = YB + ND_;                       // 8 MB, also aliases Uhi/Ulo
    unsigned short* Uhi = (unsigned short*)Zb;  // ND ushorts = 4 MB
    unsigned short* Ulo = Uhi + ND_;            // ND ushorts = 4 MB
    float* TS = out_skill;                      // sparse-stack temp in output slot
    float* ROWMAX = Zb + ND_;
    float* ROWINV = ROWMAX + N_;
    float* COLSUM = ROWINV + N_;
    float* DISD = COLSUM + N_;
    float* DEGS = DISD + N_;
    float* DISS = DEGS + N_;
    float* ENORM = DISS + N_;
    int* CNT = (int*)(ENORM + E_);
    int* CURS = CNT + N_;
    int* OFFS = CURS + N_;
    int* SORTED = OFFS + (N_ + 1);
    int* NNZ = SORTED + E_;
    int* NZR = NNZ + 1;
    int* NZC = NZR + CAP_;
    float* NZV = (float*)(NZC + CAP_);

    const int* esrc = eidx;
    const int* edst = eidx + E_;

    // fuse + adaptive adjacency (split-bf16 MFMA for U U^T)
    k_fuse<<<dim3(63, 4), 256, 0, stream>>>(emb1, demand, supply, fuseW, fuseB, U);
    k_split<<<ND_ / 1024, 256, 0, stream>>>(U, Uhi, Ulo);
    k_s_mfma<<<dim3(63, 63), 256, 0, stream>>>(Uhi, Ulo, pred);
    k_rowstat<<<N_, 256, 0, stream>>>(pred, ROWMAX, ROWINV);
    hipMemsetAsync(COLSUM, 0, N_ * sizeof(float), stream);
    hipMemsetAsync(NNZ, 0, sizeof(int), stream);
    k_softrelu<<<dim3(32, 16), 256, 0, stream>>>(pred, ROWMAX, ROWINV, COLSUM,
                                                 NNZ, NZR, NZC, NZV);
    k_disd<<<32, 256, 0, stream>>>(COLSUM, DISD);

    // dense GCN stack — sparse aggregation (nnz <= 4*N mathematically)
    const float* told = U;
    for (int l = 0; l < 2; ++l) {
        k_xw<<<dim3(63, 4), 256, 0, stream>>>(told, g0W + l * D_ * D_, DISD, YB);
        hipMemsetAsync(Zb, 0, (size_t)ND_ * sizeof(float), stream);
        k_zsp<<<CAP_ / 4, 256, 0, stream>>>(NNZ, NZR, NZC, NZV, YB, Zb);
        k_dfinish<<<2000, 256, 0, stream>>>(Zb, YB, DISD, g0B + l * D_, told, TD);
        told = TD;
    }

    // sparse provided-graph GCN stack
    hipMemsetAsync(CNT, 0, 2 * N_ * sizeof(int), stream);  // CNT + CURS
    hipMemsetAsync(DEGS, 0, N_ * sizeof(float), stream);
    k_hist<<<E_ / 256, 256, 0, stream>>>(edst, CNT);
    k_scan<<<1, 1024, 0, stream>>>(CNT, OFFS);
    k_scatter<<<E_ / 256, 256, 0, stream>>>(edst, OFFS, CURS, SORTED);
    k_degs<<<E_ / 256, 256, 0, stream>>>(edst, eattr, DEGS);
    k_diss<<<32, 256, 0, stream>>>(DEGS, DISS);
    k_enorm<<<E_ / 256, 256, 0, stream>>>(esrc, edst, eattr, DISS, ENORM);

    told = U;
    for (int l = 0; l < 2; ++l) {
        k_xw<<<dim3(63, 4), 256, 0, stream>>>(told, g1W + l * D_ * D_, nullptr, YB);
        k_sfinish<<<N_, 256, 0, stream>>>(OFFS, SORTED, ENORM, esrc, YB, DISS,
                                          g1B + l * D_, told, TS);
        told = TS;
    }

    // outputs: out_skill (=TS) += TD ; emb1 passthrough
    k_combine<<<2000, 256, 0, stream>>>(TD, out_skill);
    hipMemcpyAsync(out, emb1, (size_t)ND_ * sizeof(float), hipMemcpyDeviceToDevice, stream);
}

// Round 5
// 1185.184 us; speedup vs baseline: 2.3562x; 1.0974x over previous
//
#include <hip/hip_runtime.h>
#include <math.h>

#define N_ 8000
#define T_ 16
#define D_ 256
#define E_ 256000
#define ND_ (N_*D_)
#define CAP_ 32768   // nnz(pred) <= 4 per row * 8000 rows, mathematically

typedef __attribute__((ext_vector_type(8))) short bf16x8;
typedef __attribute__((ext_vector_type(4))) float f32x4;

// ---------------------------------------------------------------------------
// fuse: U = concat(emb1, demand[:, -1], supply[:, -1]) @ fuse_W + fuse_b
__global__ __launch_bounds__(256) void k_fuse(
    const float* __restrict__ emb1, const float* __restrict__ demand,
    const float* __restrict__ supply, const float* __restrict__ W,
    const float* __restrict__ b, float* __restrict__ U)
{
    __shared__ float As[16][132];
    __shared__ float Bs[16][68];
    const int t = threadIdx.x;
    const int tx = t & 15, ty = t >> 4;
    const int m0 = blockIdx.x * 128, n0 = blockIdx.y * 64;
    float acc[8][4] = {};
    for (int k0 = 0; k0 < 768; k0 += 16) {
#pragma unroll
        for (int i = 0; i < 2; ++i) {
            int f = t + i * 256;
            int row = f >> 2;
            int kg = (f & 3) << 2;
            int gr = m0 + row;
            float4 a = make_float4(0.f, 0.f, 0.f, 0.f);
            if (gr < N_) {
                int k = k0 + kg;
                int kk = k & 255;
                const float* src = (k < 256) ? &emb1[gr * 256 + kk]
                               : (k < 512) ? &demand[gr * 4096 + 3840 + kk]
                                           : &supply[gr * 4096 + 3840 + kk];
                a = *(const float4*)src;
            }
            As[kg + 0][row] = a.x; As[kg + 1][row] = a.y;
            As[kg + 2][row] = a.z; As[kg + 3][row] = a.w;
        }
        {
            float4 bb = *(const float4*)&W[(k0 + (t >> 4)) * 256 + n0 + (t & 15) * 4];
            *(float4*)&Bs[t >> 4][(t & 15) * 4] = bb;
        }
        __syncthreads();
#pragma unroll
        for (int k = 0; k < 16; ++k) {
            float4 a0 = *(const float4*)&As[k][ty * 8];
            float4 a1 = *(const float4*)&As[k][ty * 8 + 4];
            float4 b0 = *(const float4*)&Bs[k][tx * 4];
            float ar[8] = {a0.x, a0.y, a0.z, a0.w, a1.x, a1.y, a1.z, a1.w};
            float br[4] = {b0.x, b0.y, b0.z, b0.w};
#pragma unroll
            for (int ii = 0; ii < 8; ++ii)
#pragma unroll
                for (int jj = 0; jj < 4; ++jj)
                    acc[ii][jj] = fmaf(ar[ii], br[jj], acc[ii][jj]);
        }
        __syncthreads();
    }
#pragma unroll
    for (int ii = 0; ii < 8; ++ii) {
        int gm = m0 + ty * 8 + ii;
        if (gm >= N_) continue;
        int gn = n0 + tx * 4;
        float4 o;
        o.x = acc[ii][0] + b[gn + 0];
        o.y = acc[ii][1] + b[gn + 1];
        o.z = acc[ii][2] + b[gn + 2];
        o.w = acc[ii][3] + b[gn + 3];
        *(float4*)&U[gm * 256 + gn] = o;
    }
}

// ---------------------------------------------------------------------------
// split U (fp32) into hi/lo bf16 (round-to-nearest-even): U ~= hi + lo
__device__ __forceinline__ unsigned short f2bf(float f, float* back) {
    union { float f; unsigned u; } c; c.f = f;
    unsigned r = (c.u + 0x7fffu + ((c.u >> 16) & 1u)) & 0xffff0000u;
    union { unsigned u; float f; } o; o.u = r;
    *back = o.f;
    return (unsigned short)(r >> 16);
}

__global__ void k_split(const float* __restrict__ U, unsigned short* __restrict__ hi,
                        unsigned short* __restrict__ lo)
{
    int i = (blockIdx.x * 256 + threadIdx.x) * 4;
    float4 u = *(const float4*)&U[i];
    float bh;
    unsigned short h0 = f2bf(u.x, &bh); float l0f = u.x - bh;
    unsigned short h1 = f2bf(u.y, &bh); float l1f = u.y - bh;
    unsigned short h2 = f2bf(u.z, &bh); float l2f = u.z - bh;
    unsigned short h3 = f2bf(u.w, &bh); float l3f = u.w - bh;
    unsigned short l0 = f2bf(l0f, &bh);
    unsigned short l1 = f2bf(l1f, &bh);
    unsigned short l2 = f2bf(l2f, &bh);
    unsigned short l3 = f2bf(l3f, &bh);
    uint2 hv, lv;
    hv.x = (unsigned)h0 | ((unsigned)h1 << 16);
    hv.y = (unsigned)h2 | ((unsigned)h3 << 16);
    lv.x = (unsigned)l0 | ((unsigned)l1 << 16);
    lv.y = (unsigned)l2 | ((unsigned)l3 << 16);
    *(uint2*)&hi[i] = hv;
    *(uint2*)&lo[i] = lv;
}

// ---------------------------------------------------------------------------
// S = U @ U^T via split-bf16 MFMA: S ~= hi*hi + hi*lo + lo*hi (fp32 acc).
// block 128x128, 4 waves 2x2, wave 64x64 = 4x4 mfma_f32_16x16x32_bf16 tiles.
__global__ __launch_bounds__(256) void k_s_mfma(
    const unsigned short* __restrict__ Uhi, const unsigned short* __restrict__ Ulo,
    float* __restrict__ S)
{
    __shared__ unsigned short Ah[4][128][8];   // [kgroup][row][j] 8KB each
    __shared__ unsigned short Al[4][128][8];
    __shared__ unsigned short Bh[4][128][8];
    __shared__ unsigned short Bl[4][128][8];
    const int t = threadIdx.x;
    const int wave = t >> 6, lane = t & 63;
    const int wr = wave >> 1, wc = wave & 1;
    const int i0 = blockIdx.x * 128, j0 = blockIdx.y * 128;
    const int g = lane >> 4, rr = lane & 15;

    f32x4 acc[4][4];
#pragma unroll
    for (int m = 0; m < 4; ++m)
#pragma unroll
        for (int n = 0; n < 4; ++n) acc[m][n] = (f32x4){0.f, 0.f, 0.f, 0.f};

    for (int k0 = 0; k0 < 256; k0 += 32) {
        // stage A/B hi+lo tiles: 512 chunks of 16B per part, 2 per thread
#pragma unroll
        for (int i = 0; i < 2; ++i) {
            int cid = t + i * 256;          // 0..511
            int r = cid >> 2, gg = cid & 3; // row-in-tile, kgroup
            int off = k0 + gg * 8;
            uint4 z = make_uint4(0u, 0u, 0u, 0u);
            uint4 vah = z, val = z, vbh = z, vbl = z;
            int ga = i0 + r, gb = j0 + r;
            if (ga < N_) {
                vah = *(const uint4*)&Uhi[ga * 256 + off];
                val = *(const uint4*)&Ulo[ga * 256 + off];
            }
            if (gb < N_) {
                vbh = *(const uint4*)&Uhi[gb * 256 + off];
                vbl = *(const uint4*)&Ulo[gb * 256 + off];
            }
            *(uint4*)&Ah[gg][r][0] = vah;
            *(uint4*)&Al[gg][r][0] = val;
            *(uint4*)&Bh[gg][r][0] = vbh;
            *(uint4*)&Bl[gg][r][0] = vbl;
        }
        __syncthreads();

        bf16x8 ah[4], al[4], bh[4], bl[4];
#pragma unroll
        for (int m = 0; m < 4; ++m) {
            int row = wr * 64 + m * 16 + rr;
            ah[m] = *(const bf16x8*)&Ah[g][row][0];
            al[m] = *(const bf16x8*)&Al[g][row][0];
        }
#pragma unroll
        for (int n = 0; n < 4; ++n) {
            int col = wc * 64 + n * 16 + rr;
            bh[n] = *(const bf16x8*)&Bh[g][col][0];
            bl[n] = *(const bf16x8*)&Bl[g][col][0];
        }
#pragma unroll
        for (int m = 0; m < 4; ++m)
#pragma unroll
            for (int n = 0; n < 4; ++n) {
                acc[m][n] = __builtin_amdgcn_mfma_f32_16x16x32_bf16(ah[m], bh[n], acc[m][n], 0, 0, 0);
                acc[m][n] = __builtin_amdgcn_mfma_f32_16x16x32_bf16(ah[m], bl[n], acc[m][n], 0, 0, 0);
                acc[m][n] = __builtin_amdgcn_mfma_f32_16x16x32_bf16(al[m], bh[n], acc[m][n], 0, 0, 0);
            }
        __syncthreads();
    }

    // C/D layout (HW-verified): col = lane&15, row = (lane>>4)*4 + reg
#pragma unroll
    for (int m = 0; m < 4; ++m) {
        int gi_base = i0 + wr * 64 + m * 16 + g * 4;
#pragma unroll
        for (int n = 0; n < 4; ++n) {
            int gj = j0 + wc * 64 + n * 16 + rr;
            if (gj >= N_) continue;
#pragma unroll
            for (int j = 0; j < 4; ++j) {
                int gi = gi_base + j;
                if (gi < N_) S[(size_t)gi * N_ + gj] = acc[m][n][j];
            }
        }
    }
}

// ---------------------------------------------------------------------------
// per-row max and 1/sum(exp(s-max))
__global__ __launch_bounds__(256) void k_rowstat(const float* __restrict__ S,
    float* __restrict__ rowmax, float* __restrict__ rowinv)
{
    __shared__ float red[256];
    const int r = blockIdx.x;
    const int t = threadIdx.x;
    const float* row = S + (size_t)r * N_;
    float v[32];
    float m = -3.4e38f;
#pragma unroll
    for (int ch = 0; ch < 8; ++ch) {
        int c = ch * 1024 + t * 4;
        float4 x;
        if (c < N_) x = *(const float4*)&row[c];
        else x = make_float4(-3.4e38f, -3.4e38f, -3.4e38f, -3.4e38f);
        v[ch * 4 + 0] = x.x; v[ch * 4 + 1] = x.y;
        v[ch * 4 + 2] = x.z; v[ch * 4 + 3] = x.w;
        m = fmaxf(m, fmaxf(fmaxf(x.x, x.y), fmaxf(x.z, x.w)));
    }
    red[t] = m; __syncthreads();
    for (int s = 128; s > 0; s >>= 1) { if (t < s) red[t] = fmaxf(red[t], red[t + s]); __syncthreads(); }
    m = red[0]; __syncthreads();
    float sum = 0.f;
#pragma unroll
    for (int j = 0; j < 32; ++j) sum += __expf(v[j] - m);
    red[t] = sum; __syncthreads();
    for (int s = 128; s > 0; s >>= 1) { if (t < s) red[t] += red[t + s]; __syncthreads(); }
    if (t == 0) { rowmax[r] = m; rowinv[r] = 1.0f / red[0]; }
}

// ---------------------------------------------------------------------------
// in-place pred = relu(softmax - 0.2); column sums; sparse nonzero extraction.
// float4 columns, 32-row strips, 2000 blocks for occupancy (was 512, 20% BW).
__global__ __launch_bounds__(256) void k_softrelu(float* __restrict__ S,
    const float* __restrict__ rowmax, const float* __restrict__ rowinv,
    float* __restrict__ colsum, int* __restrict__ nnz,
    int* __restrict__ NZR, int* __restrict__ NZC, float* __restrict__ NZV)
{
    int c = (blockIdx.x * 256 + threadIdx.x) * 4;
    if (c >= N_) return;
    int r0 = blockIdx.y * 32;
    float cs0 = 0.f, cs1 = 0.f, cs2 = 0.f, cs3 = 0.f;
    for (int i = 0; i < 32; ++i) {
        int r = r0 + i;
        size_t idx = (size_t)r * N_ + c;
        float4 s = *(const float4*)&S[idx];
        float rm = rowmax[r], ri = rowinv[r];
        float4 o;
        o.x = fmaxf(__expf(s.x - rm) * ri - 0.2f, 0.f);
        o.y = fmaxf(__expf(s.y - rm) * ri - 0.2f, 0.f);
        o.z = fmaxf(__expf(s.z - rm) * ri - 0.2f, 0.f);
        o.w = fmaxf(__expf(s.w - rm) * ri - 0.2f, 0.f);
        *(float4*)&S[idx] = o;
        cs0 += o.x; cs1 += o.y; cs2 += o.z; cs3 += o.w;
        if (o.x > 0.f) { int id = atomicAdd(nnz, 1); if (id < CAP_) { NZR[id] = r; NZC[id] = c + 0; NZV[id] = o.x; } }
        if (o.y > 0.f) { int id = atomicAdd(nnz, 1); if (id < CAP_) { NZR[id] = r; NZC[id] = c + 1; NZV[id] = o.y; } }
        if (o.z > 0.f) { int id = atomicAdd(nnz, 1); if (id < CAP_) { NZR[id] = r; NZC[id] = c + 2; NZV[id] = o.z; } }
        if (o.w > 0.f) { int id = atomicAdd(nnz, 1); if (id < CAP_) { NZR[id] = r; NZC[id] = c + 3; NZV[id] = o.w; } }
    }
    atomicAdd(&colsum[c + 0], cs0);
    atomicAdd(&colsum[c + 1], cs1);
    atomicAdd(&colsum[c + 2], cs2);
    atomicAdd(&colsum[c + 3], cs3);
}

__global__ void k_disd(const float* __restrict__ colsum, float* __restrict__ dis)
{
    int c = blockIdx.x * 256 + threadIdx.x;
    if (c < N_) dis[c] = 1.0f / sqrtf(colsum[c] + 1.0f);
}

// ---------------------------------------------------------------------------
// Out[m][n] = (scale?scale[m]:1) * sum_k A[m][k]*W[k][n]
__global__ __launch_bounds__(256) void k_xw(const float* __restrict__ A,
    const float* __restrict__ W, const float* __restrict__ scale, float* __restrict__ Out)
{
    __shared__ float As[16][132];
    __shared__ float Bs[16][68];
    const int t = threadIdx.x;
    const int tx = t & 15, ty = t >> 4;
    const int m0 = blockIdx.x * 128, n0 = blockIdx.y * 64;
    float acc[8][4] = {};
    for (int k0 = 0; k0 < 256; k0 += 16) {
#pragma unroll
        for (int i = 0; i < 2; ++i) {
            int f = t + i * 256;
            int row = f >> 2;
            int kg = (f & 3) << 2;
            int gr = m0 + row;
            float4 a = make_float4(0.f, 0.f, 0.f, 0.f);
            if (gr < N_) a = *(const float4*)&A[gr * 256 + k0 + kg];
            As[kg + 0][row] = a.x; As[kg + 1][row] = a.y;
            As[kg + 2][row] = a.z; As[kg + 3][row] = a.w;
        }
        {
            float4 bb = *(const float4*)&W[(k0 + (t >> 4)) * 256 + n0 + (t & 15) * 4];
            *(float4*)&Bs[t >> 4][(t & 15) * 4] = bb;
        }
        __syncthreads();
#pragma unroll
        for (int k = 0; k < 16; ++k) {
            float4 a0 = *(const float4*)&As[k][ty * 8];
            float4 a1 = *(const float4*)&As[k][ty * 8 + 4];
            float4 b0 = *(const float4*)&Bs[k][tx * 4];
            float ar[8] = {a0.x, a0.y, a0.z, a0.w, a1.x, a1.y, a1.z, a1.w};
            float br[4] = {b0.x, b0.y, b0.z, b0.w};
#pragma unroll
            for (int ii = 0; ii < 8; ++ii)
#pragma unroll
                for (int jj = 0; jj < 4; ++jj)
                    acc[ii][jj] = fmaf(ar[ii], br[jj], acc[ii][jj]);
        }
        __syncthreads();
    }
#pragma unroll
    for (int ii = 0; ii < 8; ++ii) {
        int gm = m0 + ty * 8 + ii;
        if (gm >= N_) continue;
        float s = scale ? scale[gm] : 1.0f;
        float4 o = make_float4(acc[ii][0] * s, acc[ii][1] * s, acc[ii][2] * s, acc[ii][3] * s);
        *(float4*)&Out[gm * 256 + n0 + tx * 4] = o;
    }
}

// ---------------------------------------------------------------------------
// sparse dense-graph aggregation: Z[c,:] += v * Y[r,:] per nonzero (1 wave each)
__global__ __launch_bounds__(256) void k_zsp(const int* __restrict__ nnz,
    const int* __restrict__ NZR, const int* __restrict__ NZC, const float* __restrict__ NZV,
    const float* __restrict__ Y, float* __restrict__ Z)
{
    int n = *nnz; if (n > CAP_) n = CAP_;
    int id = blockIdx.x * 4 + (threadIdx.x >> 6);
    if (id >= n) return;
    int r = NZR[id], c = NZC[id];
    float v = NZV[id];
    int lane = threadIdx.x & 63;
    float4 y = *(const float4*)&Y[r * 256 + lane * 4];
    float* z = &Z[c * 256 + lane * 4];
    atomicAdd(z + 0, v * y.x);
    atomicAdd(z + 1, v * y.y);
    atomicAdd(z + 2, v * y.z);
    atomicAdd(z + 3, v * y.w);
}

// t_new = 0.9*(dis[c]*(z+y) + b) + 0.1*t_old
__global__ void k_dfinish(const float* __restrict__ Zb, const float* __restrict__ Yb,
    const float* __restrict__ disd, const float* __restrict__ b,
    const float* __restrict__ told, float* __restrict__ tnew)
{
    int i = blockIdx.x * 256 + threadIdx.x;
    int idx = i * 4;
    int c = idx >> 8;
    int d = idx & 255;
    float dc = disd[c];
    float4 zv = *(const float4*)&Zb[idx];
    float4 yv = *(const float4*)&Yb[idx];
    float4 tv = *(const float4*)&told[idx];
    float4 bb = *(const float4*)&b[d];
    float4 o;
    o.x = 0.9f * (dc * (zv.x + yv.x) + bb.x) + 0.1f * tv.x;
    o.y = 0.9f * (dc * (zv.y + yv.y) + bb.y) + 0.1f * tv.y;
    o.z = 0.9f * (dc * (zv.z + yv.z) + bb.z) + 0.1f * tv.z;
    o.w = 0.9f * (dc * (zv.w + yv.w) + bb.w) + 0.1f * tv.w;
    *(float4*)&tnew[idx] = o;
}

// ---------------------------------------------------------------------------
// sparse provided graph: counting sort by dst, then per-node aggregation
__global__ void k_hist(const int* __restrict__ dst, int* __restrict__ cnt)
{
    int e = blockIdx.x * 256 + threadIdx.x;
    if (e < E_) atomicAdd(&cnt[dst[e]], 1);
}

__global__ __launch_bounds__(1024) void k_scan(const int* __restrict__ cnt, int* __restrict__ offs)
{
    __shared__ int sh[1024];
    int t = threadIdx.x;
    int base = t * 8;
    int v[8];
    int s = 0;
#pragma unroll
    for (int j = 0; j < 8; ++j) {
        v[j] = s;
        int bb = base + j;
        s += (bb < N_) ? cnt[bb] : 0;
    }
    sh[t] = s;
    __syncthreads();
    for (int o = 1; o < 1024; o <<= 1) {
        int x = sh[t];
        int y = (t >= o) ? sh[t - o] : 0;
        __syncthreads();
        sh[t] = x + y;
        __syncthreads();
    }
    int pre = (t == 0) ? 0 : sh[t - 1];
#pragma unroll
    for (int j = 0; j < 8; ++j) {
        int bb = base + j;
        if (bb < N_) offs[bb] = pre + v[j];
    }
    if (t == 1023) offs[N_] = sh[1023];
}

__global__ void k_scatter(const int* __restrict__ dst, const int* __restrict__ offs,
    int* __restrict__ curs, int* __restrict__ sorted)
{
    int e = blockIdx.x * 256 + threadIdx.x;
    if (e < E_) {
        int d = dst[e];
        int pos = offs[d] + atomicAdd(&curs[d], 1);
        sorted[pos] = e;
    }
}

__global__ void k_degs(const int* __restrict__ dst, const float* __restrict__ attr,
    float* __restrict__ degs)
{
    int e = blockIdx.x * 256 + threadIdx.x;
    if (e < E_) atomicAdd(&degs[dst[e]], attr[e]);
}

__global__ void k_diss(const float* __restrict__ degs, float* __restrict__ dis)
{
    int n = blockIdx.x * 256 + threadIdx.x;
    if (n < N_) dis[n] = 1.0f / sqrtf(degs[n] + 1.0f);
}

__global__ void k_enorm(const int* __restrict__ src, const int* __restrict__ dst,
    const float* __restrict__ attr, const float* __restrict__ dis, float* __restrict__ enorm)
{
    int e = blockIdx.x * 256 + threadIdx.x;
    if (e < E_) enorm[e] = dis[src[e]] * attr[e] * dis[dst[e]];
}

__global__ __launch_bounds__(256) void k_sfinish(const int* __restrict__ offs,
    const int* __restrict__ sorted, const float* __restrict__ enorm,
    const int* __restrict__ src, const float* __restrict__ xw,
    const float* __restrict__ diss, const float* __restrict__ b,
    const float* __restrict__ told, float* __restrict__ tnew)
{
    int n = blockIdx.x;
    int t = threadIdx.x;
    float acc = 0.f;
    int beg = offs[n], end = offs[n + 1];
    for (int i = beg; i < end; ++i) {
        int e = sorted[i];
        float w = enorm[e];
        int s = src[e];
        acc += w * xw[s * 256 + t];
    }
    float sn = diss[n];
    sn *= sn;
    float out = acc + sn * xw[n * 256 + t] + b[t];
    tnew[n * 256 + t] = 0.9f * out + 0.1f * told[n * 256 + t];
}

// o += a (in-place add into skill_embs output slot)
__global__ void k_combine(const float* __restrict__ a, float* __restrict__ o)
{
    int i = blockIdx.x * 256 + threadIdx.x;
    int idx = i * 4;
    float4 x = *(const float4*)&a[idx];
    float4 y = *(const float4*)&o[idx];
    *(float4*)&o[idx] = make_float4(x.x + y.x, x.y + y.y, x.z + y.z, x.w + y.w);
}

// ---------------------------------------------------------------------------
extern "C" void kernel_launch(void* const* d_in, const int* in_sizes, int n_in,
                              void* d_out, int out_size, void* d_ws, size_t ws_size,
                              hipStream_t stream)
{
    const float* demand = (const float*)d_in[0];
    const float* supply = (const float*)d_in[1];
    const int* eidx = (const int*)d_in[2];
    const float* eattr = (const float*)d_in[3];
    const float* emb1 = (const float*)d_in[4];
    const float* fuseW = (const float*)d_in[5];
    const float* fuseB = (const float*)d_in[6];
    const float* g0W = (const float*)d_in[7];
    const float* g0B = (const float*)d_in[8];
    const float* g1W = (const float*)d_in[9];
    const float* g1B = (const float*)d_in[10];

    float* out = (float*)d_out;
    float* out_skill = out + ND_;
    float* pred = out + 2 * (size_t)ND_;

    float* ws = (float*)d_ws;
    float* U = ws;
    float* TD = U + ND_;
    float* YB = TD + ND_;
    float* Zb = YB + ND_;                       // 8 MB, also aliases Uhi/Ulo
    unsigned short* Uhi = (unsigned short*)Zb;  // ND ushorts = 4 MB
    unsigned short* Ulo = Uhi + ND_;            // ND ushorts = 4 MB
    float* TS = out_skill;                      // sparse-stack temp in output slot
    float* ROWMAX = Zb + ND_;
    float* ROWINV = ROWMAX + N_;
    float* COLSUM = ROWINV + N_;
    float* DISD = COLSUM + N_;
    float* DEGS = DISD + N_;
    float* DISS = DEGS + N_;
    float* ENORM = DISS + N_;
    int* CNT = (int*)(ENORM + E_);
    int* CURS = CNT + N_;
    int* OFFS = CURS + N_;
    int* SORTED = OFFS + (N_ + 1);
    int* NNZ = SORTED + E_;
    int* NZR = NNZ + 1;
    int* NZC = NZR + CAP_;
    float* NZV = (float*)(NZC + CAP_);

    const int* esrc = eidx;
    const int* edst = eidx + E_;

    // fuse + adaptive adjacency (split-bf16 MFMA for U U^T)
    k_fuse<<<dim3(63, 4), 256, 0, stream>>>(emb1, demand, supply, fuseW, fuseB, U);
    k_split<<<ND_ / 1024, 256, 0, stream>>>(U, Uhi, Ulo);
    k_s_mfma<<<dim3(63, 63), 256, 0, stream>>>(Uhi, Ulo, pred);
    k_rowstat<<<N_, 256, 0, stream>>>(pred, ROWMAX, ROWINV);
    hipMemsetAsync(COLSUM, 0, N_ * sizeof(float), stream);
    hipMemsetAsync(NNZ, 0, sizeof(int), stream);
    k_softrelu<<<dim3(8, 250), 256, 0, stream>>>(pred, ROWMAX, ROWINV, COLSUM,
                                                 NNZ, NZR, NZC, NZV);
    k_disd<<<32, 256, 0, stream>>>(COLSUM, DISD);

    // dense GCN stack — sparse aggregation (nnz <= 4*N mathematically)
    const float* told = U;
    for (int l = 0; l < 2; ++l) {
        k_xw<<<dim3(63, 4), 256, 0, stream>>>(told, g0W + l * D_ * D_, DISD, YB);
        hipMemsetAsync(Zb, 0, (size_t)ND_ * sizeof(float), stream);
        k_zsp<<<CAP_ / 4, 256, 0, stream>>>(NNZ, NZR, NZC, NZV, YB, Zb);
        k_dfinish<<<2000, 256, 0, stream>>>(Zb, YB, DISD, g0B + l * D_, told, TD);
        told = TD;
    }

    // sparse provided-graph GCN stack
    hipMemsetAsync(CNT, 0, 2 * N_ * sizeof(int), stream);  // CNT + CURS
    hipMemsetAsync(DEGS, 0, N_ * sizeof(float), stream);
    k_hist<<<E_ / 256, 256, 0, stream>>>(edst, CNT);
    k_scan<<<1, 1024, 0, stream>>>(CNT, OFFS);
    k_scatter<<<E_ / 256, 256, 0, stream>>>(edst, OFFS, CURS, SORTED);
    k_degs<<<E_ / 256, 256, 0, stream>>>(edst, eattr, DEGS);
    k_diss<<<32, 256, 0, stream>>>(DEGS, DISS);
    k_enorm<<<E_ / 256, 256, 0, stream>>>(esrc, edst, eattr, DISS, ENORM);

    told = U;
    for (int l = 0; l < 2; ++l) {
        k_xw<<<dim3(63, 4), 256, 0, stream>>>(told, g1W + l * D_ * D_, nullptr, YB);
        k_sfinish<<<N_, 256, 0, stream>>>(OFFS, SORTED, ENORM, esrc, YB, DISS,
                                          g1B + l * D_, told, TS);
        told = TS;
    }

    // outputs: out_skill (=TS) += TD ; emb1 passthrough
    k_combine<<<2000, 256, 0, stream>>>(TD, out_skill);
    hipMemcpyAsync(out, emb1, (size_t)ND_ * sizeof(float), hipMemcpyDeviceToDevice, stream);
}